// Round 6
// baseline (209.520 us; speedup 1.0000x reference)
//
#include <hip/hip_runtime.h>

// DynamicMaskHead: 128 instances, per-instance MLP 10->8->8->1 over 160x160 px.
// features: fp32 [1, 128*10, 160, 160] -> [128][10][25600]
// params:   fp32 [128, 169]  w0[80] w1[64] w2[8] b0[8] b1[8] b2[1]
// out:      fp32 [128, 1, 160, 160]
//
// R6 = MEASUREMENT ROUND: same kernel as R5, launched TWICE (idempotent,
// identical output). dur_us(R6) - dur_us(R5) = exact kernel time K, with
// the fixed harness re-poison/restore overhead H cancelled out.
//   K ~= 21-25 us -> kernel at memory roofline, bench is harness-dominated.
//   K ~= 60 us   -> 3x headroom, attack the memory path next round.

#define N_INST 128
#define C_IN   10
#define CH     8
#define HW     25600   // 160*160
#define PPT    4       // pixels per thread
#define BLK    256
#define CHUNKS 25      // 25600 / (256*4)

typedef float f4 __attribute__((ext_vector_type(4)));

__global__ __launch_bounds__(BLK, 2)
void DynamicMaskHead_kernel(const float* __restrict__ feat,
                            const float* __restrict__ params,
                            float* __restrict__ out)
{
    __shared__ float sp[169];
    const int inst = blockIdx.y;
    const int tid  = threadIdx.x;

    if (tid < 169) sp[tid] = params[inst * 169 + tid];
    __syncthreads();

    const int p0 = blockIdx.x * (BLK * PPT) + tid * PPT;
    const float* fb = feat + (size_t)inst * C_IN * HW + p0;

    // Layer-1 accumulators, init with bias b0 = sp[152+o]
    float h1[CH][PPT];
#pragma unroll
    for (int o = 0; o < CH; ++o) {
        const float b = sp[152 + o];
#pragma unroll
        for (int j = 0; j < PPT; ++j) h1[o][j] = b;
    }

    // Two batches of 5 channels: 5 nontemporal 16B loads in flight.
    f4 raw[5];
#pragma unroll
    for (int half = 0; half < 2; ++half) {
        const int kb = half * 5;
#pragma unroll
        for (int k = 0; k < 5; ++k)
            raw[k] = __builtin_nontemporal_load(
                (const f4*)(fb + (size_t)(kb + k) * HW));
#pragma unroll
        for (int k = 0; k < 5; ++k) {
            const float xv[PPT] = { raw[k].x, raw[k].y, raw[k].z, raw[k].w };
#pragma unroll
            for (int o = 0; o < CH; ++o) {
                const float w = sp[o * 10 + (kb + k)];
#pragma unroll
                for (int j = 0; j < PPT; ++j)
                    h1[o][j] = fmaf(w, xv[j], h1[o][j]);
            }
        }
    }
#pragma unroll
    for (int o = 0; o < CH; ++o)
#pragma unroll
        for (int j = 0; j < PPT; ++j) h1[o][j] = fmaxf(h1[o][j], 0.f);

    // Layer 2: h2 = relu(W1 h1 + b1); W1[o][k]=sp[80+o*8+k], b1=sp[160+o]
    float h2[CH][PPT];
#pragma unroll
    for (int o = 0; o < CH; ++o) {
        const float b = sp[160 + o];
#pragma unroll
        for (int j = 0; j < PPT; ++j) h2[o][j] = b;
    }
#pragma unroll
    for (int k = 0; k < CH; ++k) {
#pragma unroll
        for (int o = 0; o < CH; ++o) {
            const float w = sp[80 + o * 8 + k];
#pragma unroll
            for (int j = 0; j < PPT; ++j) h2[o][j] = fmaf(w, h1[k][j], h2[o][j]);
        }
    }
#pragma unroll
    for (int o = 0; o < CH; ++o)
#pragma unroll
        for (int j = 0; j < PPT; ++j) h2[o][j] = fmaxf(h2[o][j], 0.f);

    // Layer 3: out = W2 h2 + b2; W2[k]=sp[144+k], b2=sp[168]
    float ov[PPT];
#pragma unroll
    for (int j = 0; j < PPT; ++j) ov[j] = sp[168];
#pragma unroll
    for (int k = 0; k < CH; ++k) {
        const float w = sp[144 + k];
#pragma unroll
        for (int j = 0; j < PPT; ++j) ov[j] = fmaf(w, h2[k][j], ov[j]);
    }

    f4 res = { ov[0], ov[1], ov[2], ov[3] };
    __builtin_nontemporal_store(res, (f4*)(out + (size_t)inst * HW + p0));
}

extern "C" void kernel_launch(void* const* d_in, const int* in_sizes, int n_in,
                              void* d_out, int out_size, void* d_ws, size_t ws_size,
                              hipStream_t stream) {
    const float* feat   = (const float*)d_in[0];
    const float* params = (const float*)d_in[1];
    float* out          = (float*)d_out;

    dim3 grid(CHUNKS, N_INST);
    dim3 block(BLK);
    // Launched twice on purpose this round: K = dur(R6) - dur(R5).
    hipLaunchKernelGGL(DynamicMaskHead_kernel, grid, block, 0, stream,
                       feat, params, out);
    hipLaunchKernelGGL(DynamicMaskHead_kernel, grid, block, 0, stream,
                       feat, params, out);
}

// Round 7
// 186.178 us; speedup vs baseline: 1.1254x; 1.1254x over previous
//
#include <hip/hip_runtime.h>

// DynamicMaskHead: 128 instances, per-instance MLP 10->8->8->1 over 160x160 px.
// features: fp32 [1, 128*10, 160, 160] -> [128][10][25600]
// params:   fp32 [128, 169]  w0[80] w1[64] w2[8] b0[8] b1[8] b2[1]
// out:      fp32 [128, 1, 160, 160]
//
// FINAL (R5 kernel, single launch). Measured via R5/R6 differential probe:
// K = 209.52 - 185.23 = 24.3 us for 144.2 MB mandatory traffic = 5.93 TB/s
// = 94% of the 6.3 TB/s achievable-copy ceiling. Byte count is irreducible
// (every feature element read exactly once, output written once); compute
// (1 GFLOP ~ 6 us VALU) fully hidden. Bench dur_us ~185 is dominated by
// ~160 us of harness ws-poison/input-restore fills outside our control.

#define N_INST 128
#define C_IN   10
#define CH     8
#define HW     25600   // 160*160
#define PPT    4       // pixels per thread
#define BLK    256
#define CHUNKS 25      // 25600 / (256*4)

typedef float f4 __attribute__((ext_vector_type(4)));

__global__ __launch_bounds__(BLK, 2)
void DynamicMaskHead_kernel(const float* __restrict__ feat,
                            const float* __restrict__ params,
                            float* __restrict__ out)
{
    __shared__ float sp[169];
    const int inst = blockIdx.y;
    const int tid  = threadIdx.x;

    if (tid < 169) sp[tid] = params[inst * 169 + tid];
    __syncthreads();

    const int p0 = blockIdx.x * (BLK * PPT) + tid * PPT;
    const float* fb = feat + (size_t)inst * C_IN * HW + p0;

    // Layer-1 accumulators, init with bias b0 = sp[152+o]
    float h1[CH][PPT];
#pragma unroll
    for (int o = 0; o < CH; ++o) {
        const float b = sp[152 + o];
#pragma unroll
        for (int j = 0; j < PPT; ++j) h1[o][j] = b;
    }

    // Two batches of 5 channels: 5 nontemporal 16B loads in flight,
    // spill-proof register budget (~70 VGPR peak).
    f4 raw[5];
#pragma unroll
    for (int half = 0; half < 2; ++half) {
        const int kb = half * 5;
#pragma unroll
        for (int k = 0; k < 5; ++k)
            raw[k] = __builtin_nontemporal_load(
                (const f4*)(fb + (size_t)(kb + k) * HW));
#pragma unroll
        for (int k = 0; k < 5; ++k) {
            const float xv[PPT] = { raw[k].x, raw[k].y, raw[k].z, raw[k].w };
#pragma unroll
            for (int o = 0; o < CH; ++o) {
                const float w = sp[o * 10 + (kb + k)];
#pragma unroll
                for (int j = 0; j < PPT; ++j)
                    h1[o][j] = fmaf(w, xv[j], h1[o][j]);
            }
        }
    }
#pragma unroll
    for (int o = 0; o < CH; ++o)
#pragma unroll
        for (int j = 0; j < PPT; ++j) h1[o][j] = fmaxf(h1[o][j], 0.f);

    // Layer 2: h2 = relu(W1 h1 + b1); W1[o][k]=sp[80+o*8+k], b1=sp[160+o]
    float h2[CH][PPT];
#pragma unroll
    for (int o = 0; o < CH; ++o) {
        const float b = sp[160 + o];
#pragma unroll
        for (int j = 0; j < PPT; ++j) h2[o][j] = b;
    }
#pragma unroll
    for (int k = 0; k < CH; ++k) {
#pragma unroll
        for (int o = 0; o < CH; ++o) {
            const float w = sp[80 + o * 8 + k];
#pragma unroll
            for (int j = 0; j < PPT; ++j) h2[o][j] = fmaf(w, h1[k][j], h2[o][j]);
        }
    }
#pragma unroll
    for (int o = 0; o < CH; ++o)
#pragma unroll
        for (int j = 0; j < PPT; ++j) h2[o][j] = fmaxf(h2[o][j], 0.f);

    // Layer 3: out = W2 h2 + b2; W2[k]=sp[144+k], b2=sp[168]
    float ov[PPT];
#pragma unroll
    for (int j = 0; j < PPT; ++j) ov[j] = sp[168];
#pragma unroll
    for (int k = 0; k < CH; ++k) {
        const float w = sp[144 + k];
#pragma unroll
        for (int j = 0; j < PPT; ++j) ov[j] = fmaf(w, h2[k][j], ov[j]);
    }

    f4 res = { ov[0], ov[1], ov[2], ov[3] };
    __builtin_nontemporal_store(res, (f4*)(out + (size_t)inst * HW + p0));
}

extern "C" void kernel_launch(void* const* d_in, const int* in_sizes, int n_in,
                              void* d_out, int out_size, void* d_ws, size_t ws_size,
                              hipStream_t stream) {
    const float* feat   = (const float*)d_in[0];
    const float* params = (const float*)d_in[1];
    float* out          = (float*)d_out;

    dim3 grid(CHUNKS, N_INST);
    dim3 block(BLK);
    hipLaunchKernelGGL(DynamicMaskHead_kernel, grid, block, 0, stream,
                       feat, params, out);
}